// Round 6
// baseline (160.550 us; speedup 1.0000x reference)
//
#include <hip/hip_runtime.h>

#define NA 4
#define NH 3
#define NHI 2
#define Bsz 32768
#define Ssz 256
#define Csz 16
#define Dsz 128
#define INsz 176
#define NP 20
#define KP 192
#define GT 4

typedef __bf16 v8bf __attribute__((ext_vector_type(8)));
typedef float v4f __attribute__((ext_vector_type(4)));

// ---- ws layout (bytes) ----
// X column order is REORDERED to [enc(0..127) | acs-LOO(128..175) | bias(176) | 0(177..191)],
// baked into the W1F permutation below.
#define OFF_ENC    0                    // enc_t tiled: [rt=B/16][16 chunks][lane][8bf16] = 8388608
#define OFF_ACSBF  8388608              // acs_t tiled: [plane 12][rt 2048][32][8bf16] = 12582912 (1 MiB/plane)
#define OFF_W1F    20971520             // NP*6*8*512*2       = 983040  (fragment-order, new col order)
#define OFF_ENCWF  21954560             // 8*8*512*2          = 65536   (fragment-order)
#define OFF_W2T    22020096             // NP*2048*2 bf16, layout [p][c][(dlow^c)][dtile]
#define OFF_AMX    22102016             // amx2: [plane 12][group B/64][m 16 u32] = 393216
#define OFF_ZERO   22495232             // 64 B: bf16 {1.0, 0...} then zeros (bias one-hot + zero pad)

// ---- prep ranges ----
#define N_ACSROW (NA*NH*Bsz)            // 393216
#define N_W1F   (NP*192*32)             // 122880
#define N_ENCWF (256*32)                // 8192
#define N_W2T   (NP*Csz*Dsz)            // 40960
#define N_ZERO  16
#define N_PREP  (N_ACSROW+N_W1F+N_ENCWF+N_W2T+N_ZERO)

__global__ __launch_bounds__(256) void prep_kernel(
    const float* __restrict__ acs, const float* __restrict__ encW,
    const float* __restrict__ eW1, const float* __restrict__ iW1,
    const float* __restrict__ eW2, const float* __restrict__ iW2,
    const float* __restrict__ eb1, const float* __restrict__ ib1,
    char* __restrict__ ws)
{
    long tid = (long)blockIdx.x * 256 + threadIdx.x;

    if (tid < N_ACSROW) {          // acs row: fp32->bf16 + argmax; store TILED [plane][rt][qh*16+m][8]
        const float4* src = (const float4*)(acs + (size_t)tid * 16);
        float4 f0 = src[0], f1 = src[1], f2 = src[2], f3 = src[3];
        float v[16] = {f0.x,f0.y,f0.z,f0.w, f1.x,f1.y,f1.z,f1.w,
                       f2.x,f2.y,f2.z,f2.w, f3.x,f3.y,f3.z,f3.w};
        v8bf o0, o1;
        #pragma unroll
        for (int i = 0; i < 8; ++i) { o0[i] = (__bf16)v[i]; o1[i] = (__bf16)v[8 + i]; }
        const int plane = (int)(tid >> 15);          // tid / Bsz
        const int b     = (int)(tid & 32767);
        const int rt    = b >> 4, mm = b & 15;
        char* dstb = ws + OFF_ACSBF + (size_t)plane * 1048576 + (size_t)rt * 512 + mm * 16;
        *(v8bf*)dstb         = o0;                   // cols 0..7  (chunk 0)
        *(v8bf*)(dstb + 256) = o1;                   // cols 8..15 (chunk 1)
        float best = v[0]; int bi = 0;
        #pragma unroll
        for (int c = 1; c < 16; ++c) if (v[c] > best) { best = v[c]; bi = c; }
        // amx2 packed layout: u32 per (64-row group, m); byte mt of word = argmax(row group*64+mt*16+m)
        const int grp = b >> 6, mt = (b >> 4) & 3, m = b & 15;
        ((unsigned char*)(ws + OFF_AMX))[(size_t)plane * 32768 + grp * 64 + m * 4 + mt]
            = (unsigned char)bi;
        return;
    }
    tid -= N_ACSROW;
    if (tid < N_W1F) {             // W1 -> bf16 fragment-order [p][kc][nt][lane][8], REORDERED cols:
        const int n4 = (int)(tid & 31) * 4;          // k'<128: enc (src row 48+k'); 128..175: acs (k'-128);
        const int k  = (int)((tid >> 5) % 192);      // 176: b1; else 0
        const int p  = (int)(tid / 6144);
        const float* W1; const float* B1;
        if (p < 12) { int ai = p / 3, hj = p % 3; int wi = hj * NA + ai;
                      W1 = eW1 + (size_t)wi * INsz * Dsz; B1 = eb1 + (size_t)wi * Dsz; }
        else { int qq = p - 12; int ai = qq >> 1, jj = qq & 1; int wi = jj * NA + ai;
               W1 = iW1 + (size_t)wi * INsz * Dsz; B1 = ib1 + (size_t)wi * Dsz; }
        float4 f;
        if (k < 128)        f = *(const float4*)(W1 + (size_t)(48 + k) * Dsz + n4);
        else if (k < INsz)  f = *(const float4*)(W1 + (size_t)(k - 128) * Dsz + n4);
        else if (k == INsz) f = *(const float4*)(B1 + n4);
        else                f = (float4){0.f, 0.f, 0.f, 0.f};
        const int kc = k >> 5, q = (k >> 3) & 3, j = k & 7;
        __bf16* dst = (__bf16*)(ws + OFF_W1F);
        const float fv[4] = {f.x, f.y, f.z, f.w};
        #pragma unroll
        for (int i = 0; i < 4; ++i) {
            const int n = n4 + i, nt = n >> 4, m = n & 15;
            dst[((size_t)(p * 6 + kc) * 8 + nt) * 512 + (q * 16 + m) * 8 + j] = (__bf16)fv[i];
        }
        return;
    }
    tid -= N_W1F;
    if (tid < N_ENCWF) {           // encW -> bf16 fragment-order [kc][nt][lane][8] (enc GEMM B, unchanged)
        const int n4 = (int)(tid & 31) * 4;
        const int k  = (int)(tid >> 5);
        float4 f = *(const float4*)(encW + (size_t)k * Dsz + n4);
        const int kc = k >> 5, q = (k >> 3) & 3, j = k & 7;
        __bf16* dst = (__bf16*)(ws + OFF_ENCWF);
        const float fv[4] = {f.x, f.y, f.z, f.w};
        #pragma unroll
        for (int i = 0; i < 4; ++i) {
            const int n = n4 + i, nt = n >> 4, m = n & 15;
            dst[((size_t)kc * 8 + nt) * 512 + (q * 16 + m) * 8 + j] = (__bf16)fv[i];
        }
        return;
    }
    tid -= N_ENCWF;
    if (tid < N_W2T) {             // W2 -> bf16 [p][c][(dlow^c)][dtile]  (d = dtile*16 + dlow)
        int d = (int)(tid & 127);
        int rest = (int)(tid >> 7);
        int c = rest & 15, p = rest >> 4;
        const float* W2;
        if (p < 12) { int ai = p / 3, hj = p % 3; W2 = eW2 + (size_t)(hj * NA + ai) * Dsz * Csz; }
        else { int qq = p - 12; int ai = qq >> 1, jj = qq & 1; W2 = iW2 + (size_t)(jj * NA + ai) * Dsz * Csz; }
        const int dlow = d & 15, dt = d >> 4;
        ((__bf16*)(ws + OFF_W2T))[(size_t)p * 2048 + c * 128 + ((dlow ^ c) * 8) + dt]
            = (__bf16)W2[(size_t)d * Csz + c];
        return;
    }
    tid -= N_W2T;
    if (tid < N_ZERO) {            // bias one-hot: bytes 0..15 = {1.0bf16,0...}, 16..63 = 0
        ((unsigned int*)(ws + OFF_ZERO))[tid] = (tid == 0) ? 0x00003F80u : 0u;
    }
}

// ---------------- encoder: LDS-staged sv (coalesced HBM), MFMA, per-wave transpose ----------------
// Output layout enc_t: byte = rt*4096 + s*256 + m*16 + j*2  holds enc[rt*16 + m][s*8 + j]
__global__ __launch_bounds__(256) void enc_kernel(const float* __restrict__ sv,
                                                  const float* __restrict__ encb,
                                                  char* __restrict__ ws)
{
    __shared__ __bf16 svs[64][264];      // 33.8 KB: 64 rows x 256 cols (+8 pad), bf16
    __shared__ __bf16 tb[4][16 * 136];   // 17 KB: per-wave output transpose tile

    const int t = threadIdx.x;
    const int wv = t >> 6, lane = t & 63, m = lane & 15, q = lane >> 4;
    const __bf16* encwf = (const __bf16*)(ws + OFF_ENCWF);
    char* enct = ws + OFF_ENC;

    {
        const float* src = sv + ((size_t)blockIdx.x * 64 + wv * 16) * Ssz;
        #pragma unroll
        for (int i = 0; i < 16; ++i) {
            float4 f = *(const float4*)(src + i * Ssz + lane * 4);
            __bf16* d = &svs[wv * 16 + i][lane * 4];
            d[0] = (__bf16)f.x; d[1] = (__bf16)f.y; d[2] = (__bf16)f.z; d[3] = (__bf16)f.w;
        }
    }

    v4f acc[8];
    #pragma unroll
    for (int nt = 0; nt < 8; ++nt) acc[nt] = (v4f){0.f, 0.f, 0.f, 0.f};

    #pragma unroll
    for (int kc = 0; kc < 8; ++kc) {
        v8bf af = *(const v8bf*)&svs[wv * 16 + m][kc * 32 + q * 8];
        #pragma unroll
        for (int nt = 0; nt < 8; ++nt) {
            v8bf bf = *(const v8bf*)(encwf + ((size_t)kc * 8 + nt) * 512 + lane * 8);
            acc[nt] = __builtin_amdgcn_mfma_f32_16x16x32_bf16(af, bf, acc[nt], 0, 0, 0);
        }
    }
    #pragma unroll
    for (int nt = 0; nt < 8; ++nt) {
        const float bias = encb[nt * 16 + m];
        #pragma unroll
        for (int rg = 0; rg < 4; ++rg) {
            float v = acc[nt][rg] + bias;
            v = v > 0.f ? v : 0.f;
            tb[wv][(q * 4 + rg) * 136 + nt * 16 + m] = (__bf16)v;
        }
    }
    const int rt = blockIdx.x * 4 + wv;
    #pragma unroll
    for (int kc = 0; kc < 4; ++kc) {
        v8bf v = *(const v8bf*)&tb[wv][m * 136 + kc * 32 + q * 8];
        *(v8bf*)(enct + ((size_t)(rt * 4 + kc) * 64 + lane) * 16) = v;
    }
}

// ---------------- critic: GT=4, depth-3 X prefetch (4 rotating buffers), packed amx ----------------
#define LD_E(D, KC, GG) \
  { _Pragma("unroll") \
    for (int mt_ = 0; mt_ < 4; ++mt_) \
      D[mt_] = *(const v8bf*)(encL + (GG) * 65536 + mt_ * 4096 + (KC) * 1024); }

#define LD_4(D, GG) \
  { _Pragma("unroll") \
    for (int mt_ = 0; mt_ < 4; ++mt_) \
      D[mt_] = *(const v8bf*)(a4L + (GG) * 8192 + mt_ * 512); }

#define LD_5(D, GG) \
  { _Pragma("unroll") \
    for (int mt_ = 0; mt_ < 4; ++mt_) \
      D[mt_] = *(const v8bf*)(a5L + (GG) * g5 + mt_ * s5); }

// swapped operand order: A = W1 fragment (from LDS), B = X fragment (per-lane rows)
#define MFMA_KC(AF, KC) \
  { __builtin_amdgcn_s_setprio(1); \
    _Pragma("unroll") \
    for (int nt_ = 0; nt_ < 8; ++nt_) { \
      v8bf bf_ = *(const v8bf*)&w1s[(size_t)(((KC) * 8 + nt_) * 512) + lane * 8]; \
      acc[0][nt_] = __builtin_amdgcn_mfma_f32_16x16x32_bf16(bf_, AF[0], acc[0][nt_], 0, 0, 0); \
      acc[1][nt_] = __builtin_amdgcn_mfma_f32_16x16x32_bf16(bf_, AF[1], acc[1][nt_], 0, 0, 0); \
      acc[2][nt_] = __builtin_amdgcn_mfma_f32_16x16x32_bf16(bf_, AF[2], acc[2][nt_], 0, 0, 0); \
      acc[3][nt_] = __builtin_amdgcn_mfma_f32_16x16x32_bf16(bf_, AF[3], acc[3][nt_], 0, 0, 0); \
    } \
    __builtin_amdgcn_s_setprio(0); }

#define EPILOG(GG) \
  { _Pragma("unroll") \
    for (int mt = 0; mt < 4; ++mt) { \
        const int c = (int)((cw >> (8 * mt)) & 255u); \
        const __bf16* wcb = &w2s[c * 128]; \
        float s0 = 0.f, s1 = 0.f; \
        _Pragma("unroll") \
        for (int rg = 0; rg < 4; rg += 2) { \
            const v8bf wa = *(const v8bf*)&wcb[((q * 4 + rg) ^ c) * 8]; \
            const v8bf wb = *(const v8bf*)&wcb[((q * 4 + rg + 1) ^ c) * 8]; \
            _Pragma("unroll") \
            for (int nt = 0; nt < 8; ++nt) { \
                s0 += fmaxf(acc[mt][nt][rg],     0.f) * (float)wa[nt]; \
                s1 += fmaxf(acc[mt][nt][rg + 1], 0.f) * (float)wb[nt]; \
            } \
        } \
        float tsum = s0 + s1; \
        tsum += __shfl_xor(tsum, 16, 64); \
        tsum += __shfl_xor(tsum, 32, 64); \
        if (q == 0) \
            outp[(size_t)rb * 1024 + (GG) * 256 + wv * 64 + mt * 16 + m] = tsum + b2s[c]; \
        if ((GG) + 1 < GT) { \
            _Pragma("unroll") \
            for (int nt = 0; nt < 8; ++nt) acc[mt][nt] = (v4f){0.f, 0.f, 0.f, 0.f}; \
        } \
    } }

// one g-iteration: kc0 in A_, kc1 in B_, kc2 in C_, D_ free. Next iteration uses (C_,D_,A_,B_).
#define GBODY(GG, A_, B_, C_, D_, LAST) \
  { const unsigned int cw = *(const unsigned int*)(amxL + (GG) * 256); \
    LD_E(D_, 3, GG)                      MFMA_KC(A_, 0) \
    LD_4(A_, GG)                         MFMA_KC(B_, 1) \
    LD_5(B_, GG)                         MFMA_KC(C_, 2) \
    if (!(LAST)) { LD_E(C_, 0, (GG)+1) } MFMA_KC(D_, 3) \
    if (!(LAST)) { LD_E(D_, 1, (GG)+1) } MFMA_KC(A_, 4) \
    if (!(LAST)) { LD_E(A_, 2, (GG)+1) } MFMA_KC(B_, 5) \
    EPILOG(GG) }

__global__ __launch_bounds__(256, 2) void critic_kernel(
    const float* __restrict__ eb2, const float* __restrict__ ib2,
    const char* __restrict__ ws, float* __restrict__ out)
{
    __shared__ __bf16 w1s[6 * 8 * 512];   // 48 KB W1 panel (incl. bias row), fragment order
    __shared__ __bf16 w2s[16 * 128];      // 4 KB W2 [c][(dlow^c)][dtile]
    __shared__ float  b2s[16];

    const int t = threadIdx.x;
    const int p  = blockIdx.y;
    const int rb = blockIdx.x;
    const int wv = t >> 6, lane = t & 63, m = lane & 15, q = lane >> 4;

    int ai, hj;
    const float* b2;
    float* outp;
    if (p < 12) {
        ai = p / 3; hj = p % 3;
        b2 = eb2 + (size_t)(hj * NA + ai) * Csz;
        outp = out + (size_t)(ai * NH + hj) * Bsz;
    } else {
        const int qq = p - 12; ai = qq >> 1; const int jj = qq & 1; hj = jj + 1;
        b2 = ib2 + (size_t)(jj * NA + ai) * Csz;
        outp = out + (size_t)NA * NH * Bsz + (size_t)(ai * NHI + jj) * Bsz;
    }

    const __bf16* w1f = (const __bf16*)(ws + OFF_W1F) + (size_t)p * 6 * 8 * 512;
    const __bf16* w2t = (const __bf16*)(ws + OFF_W2T) + (size_t)p * 2048;
    // packed argmax: one u32 per (64-row group, m); group = rb*16 + g*4 + wv
    const char* amxL = ws + OFF_AMX + (size_t)(ai * NH + hj) * 32768
        + ((size_t)rb * 16 + wv) * 64 + m * 4;

    // stage W1 panel (48 KB) + W2 (4 KB) + b2 into LDS
    {
        const v8bf* src = (const v8bf*)w1f;
        #pragma unroll
        for (int i = 0; i < 12; ++i)
            ((v8bf*)w1s)[i * 256 + t] = src[i * 256 + t];
        ((v8bf*)w2s)[t] = ((const v8bf*)w2t)[t];
        if (t < 16) b2s[t] = b2[t];
    }

    // slim per-lane X bases (tiled layouts -> base + immediate offsets)
    const int loo0 = 0 + (0 >= ai), loo1 = 1 + (1 >= ai), loo2 = 2 + (2 >= ai);
    const int pA = loo0 * NH + hj, pB = loo1 * NH + hj, pC = loo2 * NH + hj;
    const int rtb = rb * 64 + wv * 4;
    const char* encL = ws + OFF_ENC + (size_t)rtb * 4096 + lane * 16;
    const size_t rtoff = (size_t)rtb * 512 + (lane & 31) * 16;
    const char* a4L = ws + OFF_ACSBF + (size_t)((q < 2) ? pA : pB) * 1048576 + rtoff;
    const char* a5L; int s5, g5;
    if (q < 2) { a5L = ws + OFF_ACSBF + (size_t)pC * 1048576 + rtoff; s5 = 512; g5 = 8192; }
    else       { a5L = ws + OFF_ZERO + (q - 2) * 16;                  s5 = 0;   g5 = 0;    }

    v4f acc[4][8];
    #pragma unroll
    for (int i = 0; i < 4; ++i)
        #pragma unroll
        for (int j = 0; j < 8; ++j)
            acc[i][j] = (v4f){0.f, 0.f, 0.f, 0.f};

    // 4 rotating X buffers, depth-3 prefetch
    v8bf af0[4], af1[4], af2[4], af3[4];
    LD_E(af0, 0, 0)
    LD_E(af1, 1, 0)
    LD_E(af2, 2, 0)

    __syncthreads();

    GBODY(0, af0, af1, af2, af3, 0)
    GBODY(1, af2, af3, af0, af1, 0)
    GBODY(2, af0, af1, af2, af3, 0)
    GBODY(3, af2, af3, af0, af1, 1)
}

extern "C" void kernel_launch(void* const* d_in, const int* in_sizes, int n_in,
                              void* d_out, int out_size, void* d_ws, size_t ws_size,
                              hipStream_t stream) {
    const float* sv   = (const float*)d_in[0];
    const float* acs  = (const float*)d_in[1];
    const float* encW = (const float*)d_in[2];
    const float* encb = (const float*)d_in[3];
    const float* eW1  = (const float*)d_in[4];
    const float* eb1  = (const float*)d_in[5];
    const float* eW2  = (const float*)d_in[6];
    const float* eb2  = (const float*)d_in[7];
    const float* iW1  = (const float*)d_in[8];
    const float* ib1  = (const float*)d_in[9];
    const float* iW2  = (const float*)d_in[10];
    const float* ib2  = (const float*)d_in[11];
    float* out = (float*)d_out;
    char* ws = (char*)d_ws;

    hipLaunchKernelGGL(prep_kernel, dim3((N_PREP + 255) / 256), dim3(256), 0, stream,
                       acs, encW, eW1, iW1, eW2, iW2, eb1, ib1, ws);
    hipLaunchKernelGGL(enc_kernel, dim3(Bsz / 64), dim3(256), 0, stream, sv, encb, ws);
    hipLaunchKernelGGL(critic_kernel, dim3(Bsz / 1024, NP), dim3(256), 0, stream,
                       eb2, ib2, ws, out);
}

// Round 7
// 150.494 us; speedup vs baseline: 1.0668x; 1.0668x over previous
//
#include <hip/hip_runtime.h>

#define NA 4
#define NH 3
#define NHI 2
#define Bsz 32768
#define Ssz 256
#define Csz 16
#define Dsz 128
#define INsz 176
#define NP 20
#define KP 192
#define GT 2

typedef __bf16 v8bf __attribute__((ext_vector_type(8)));
typedef float v4f __attribute__((ext_vector_type(4)));

// ---- ws layout (bytes) ----
// X column order is REORDERED to [enc(0..127) | acs-LOO(128..175) | bias(176) | 0(177..191)],
// baked into the W1F permutation below.
#define OFF_ENC    0                    // enc_t tiled: [rt=B/16][16 chunks][lane][8bf16] = 8388608
#define OFF_ACSBF  8388608              // acs_t tiled: [plane 12][rt 2048][32][8bf16] = 12582912 (1 MiB/plane)
#define OFF_W1F    20971520             // NP*6*8*512*2       = 983040  (fragment-order, new col order)
#define OFF_ENCWF  21954560             // 8*8*512*2          = 65536   (fragment-order)
#define OFF_W2T    22020096             // NP*2048*2 bf16, layout [p][c][(dlow^c)][dtile]
#define OFF_AMX    22102016             // amx2 packed: [plane 12][group B/64][m 16] u32 = 393216
#define OFF_ZERO   22495232             // 64 B: bf16 {1.0, 0...} then zeros (bias one-hot + zero pad)

// ---- prep ranges ----
#define N_ACSROW (NA*NH*Bsz)            // 393216
#define N_W1F   (NP*192*32)             // 122880
#define N_ENCWF (256*32)                // 8192
#define N_W2T   (NP*Csz*Dsz)            // 40960
#define N_ZERO  16
#define N_PREP  (N_ACSROW+N_W1F+N_ENCWF+N_W2T+N_ZERO)

__global__ __launch_bounds__(256) void prep_kernel(
    const float* __restrict__ acs, const float* __restrict__ encW,
    const float* __restrict__ eW1, const float* __restrict__ iW1,
    const float* __restrict__ eW2, const float* __restrict__ iW2,
    const float* __restrict__ eb1, const float* __restrict__ ib1,
    char* __restrict__ ws)
{
    long tid = (long)blockIdx.x * 256 + threadIdx.x;

    if (tid < N_ACSROW) {          // acs row: fp32->bf16 + argmax; store TILED [plane][rt][qh*16+m][8]
        const float4* src = (const float4*)(acs + (size_t)tid * 16);
        float4 f0 = src[0], f1 = src[1], f2 = src[2], f3 = src[3];
        float v[16] = {f0.x,f0.y,f0.z,f0.w, f1.x,f1.y,f1.z,f1.w,
                       f2.x,f2.y,f2.z,f2.w, f3.x,f3.y,f3.z,f3.w};
        v8bf o0, o1;
        #pragma unroll
        for (int i = 0; i < 8; ++i) { o0[i] = (__bf16)v[i]; o1[i] = (__bf16)v[8 + i]; }
        const int plane = (int)(tid >> 15);          // tid / Bsz
        const int b     = (int)(tid & 32767);
        const int rt    = b >> 4, mm = b & 15;
        char* dstb = ws + OFF_ACSBF + (size_t)plane * 1048576 + (size_t)rt * 512 + mm * 16;
        *(v8bf*)dstb         = o0;                   // cols 0..7  (chunk 0)
        *(v8bf*)(dstb + 256) = o1;                   // cols 8..15 (chunk 1)
        float best = v[0]; int bi = 0;
        #pragma unroll
        for (int c = 1; c < 16; ++c) if (v[c] > best) { best = v[c]; bi = c; }
        // amx2 packed layout: u32 per (64-row group, m); byte mt of word = argmax(grp*64 + mt*16 + m)
        const int grp = b >> 6, mt = (b >> 4) & 3, m = b & 15;
        ((unsigned char*)(ws + OFF_AMX))[(size_t)plane * 32768 + grp * 64 + m * 4 + mt]
            = (unsigned char)bi;
        return;
    }
    tid -= N_ACSROW;
    if (tid < N_W1F) {             // W1 -> bf16 fragment-order [p][kc][nt][lane][8], REORDERED cols:
        const int n4 = (int)(tid & 31) * 4;          // k'<128: enc (src row 48+k'); 128..175: acs (k'-128);
        const int k  = (int)((tid >> 5) % 192);      // 176: b1; else 0
        const int p  = (int)(tid / 6144);
        const float* W1; const float* B1;
        if (p < 12) { int ai = p / 3, hj = p % 3; int wi = hj * NA + ai;
                      W1 = eW1 + (size_t)wi * INsz * Dsz; B1 = eb1 + (size_t)wi * Dsz; }
        else { int qq = p - 12; int ai = qq >> 1, jj = qq & 1; int wi = jj * NA + ai;
               W1 = iW1 + (size_t)wi * INsz * Dsz; B1 = ib1 + (size_t)wi * Dsz; }
        float4 f;
        if (k < 128)        f = *(const float4*)(W1 + (size_t)(48 + k) * Dsz + n4);
        else if (k < INsz)  f = *(const float4*)(W1 + (size_t)(k - 128) * Dsz + n4);
        else if (k == INsz) f = *(const float4*)(B1 + n4);
        else                f = (float4){0.f, 0.f, 0.f, 0.f};
        const int kc = k >> 5, q = (k >> 3) & 3, j = k & 7;
        __bf16* dst = (__bf16*)(ws + OFF_W1F);
        const float fv[4] = {f.x, f.y, f.z, f.w};
        #pragma unroll
        for (int i = 0; i < 4; ++i) {
            const int n = n4 + i, nt = n >> 4, m = n & 15;
            dst[((size_t)(p * 6 + kc) * 8 + nt) * 512 + (q * 16 + m) * 8 + j] = (__bf16)fv[i];
        }
        return;
    }
    tid -= N_W1F;
    if (tid < N_ENCWF) {           // encW -> bf16 fragment-order [kc][nt][lane][8] (enc GEMM B, unchanged)
        const int n4 = (int)(tid & 31) * 4;
        const int k  = (int)(tid >> 5);
        float4 f = *(const float4*)(encW + (size_t)k * Dsz + n4);
        const int kc = k >> 5, q = (k >> 3) & 3, j = k & 7;
        __bf16* dst = (__bf16*)(ws + OFF_ENCWF);
        const float fv[4] = {f.x, f.y, f.z, f.w};
        #pragma unroll
        for (int i = 0; i < 4; ++i) {
            const int n = n4 + i, nt = n >> 4, m = n & 15;
            dst[((size_t)kc * 8 + nt) * 512 + (q * 16 + m) * 8 + j] = (__bf16)fv[i];
        }
        return;
    }
    tid -= N_ENCWF;
    if (tid < N_W2T) {             // W2 -> bf16 [p][c][(dlow^c)][dtile]  (d = dtile*16 + dlow)
        int d = (int)(tid & 127);
        int rest = (int)(tid >> 7);
        int c = rest & 15, p = rest >> 4;
        const float* W2;
        if (p < 12) { int ai = p / 3, hj = p % 3; W2 = eW2 + (size_t)(hj * NA + ai) * Dsz * Csz; }
        else { int qq = p - 12; int ai = qq >> 1, jj = qq & 1; W2 = iW2 + (size_t)(jj * NA + ai) * Dsz * Csz; }
        const int dlow = d & 15, dt = d >> 4;
        ((__bf16*)(ws + OFF_W2T))[(size_t)p * 2048 + c * 128 + ((dlow ^ c) * 8) + dt]
            = (__bf16)W2[(size_t)d * Csz + c];
        return;
    }
    tid -= N_W2T;
    if (tid < N_ZERO) {            // bias one-hot: bytes 0..15 = {1.0bf16,0...}, 16..63 = 0
        ((unsigned int*)(ws + OFF_ZERO))[tid] = (tid == 0) ? 0x00003F80u : 0u;
    }
}

// ---------------- encoder: LDS-staged sv (coalesced HBM), MFMA, per-wave transpose ----------------
// Output layout enc_t: byte = rt*4096 + s*256 + m*16 + j*2  holds enc[rt*16 + m][s*8 + j]
__global__ __launch_bounds__(256) void enc_kernel(const float* __restrict__ sv,
                                                  const float* __restrict__ encb,
                                                  char* __restrict__ ws)
{
    __shared__ __bf16 svs[64][264];      // 33.8 KB: 64 rows x 256 cols (+8 pad), bf16
    __shared__ __bf16 tb[4][16 * 136];   // 17 KB: per-wave output transpose tile

    const int t = threadIdx.x;
    const int wv = t >> 6, lane = t & 63, m = lane & 15, q = lane >> 4;
    const __bf16* encwf = (const __bf16*)(ws + OFF_ENCWF);
    char* enct = ws + OFF_ENC;

    {
        const float* src = sv + ((size_t)blockIdx.x * 64 + wv * 16) * Ssz;
        #pragma unroll
        for (int i = 0; i < 16; ++i) {
            float4 f = *(const float4*)(src + i * Ssz + lane * 4);
            __bf16* d = &svs[wv * 16 + i][lane * 4];
            d[0] = (__bf16)f.x; d[1] = (__bf16)f.y; d[2] = (__bf16)f.z; d[3] = (__bf16)f.w;
        }
    }

    v4f acc[8];
    #pragma unroll
    for (int nt = 0; nt < 8; ++nt) acc[nt] = (v4f){0.f, 0.f, 0.f, 0.f};

    #pragma unroll
    for (int kc = 0; kc < 8; ++kc) {
        v8bf af = *(const v8bf*)&svs[wv * 16 + m][kc * 32 + q * 8];
        #pragma unroll
        for (int nt = 0; nt < 8; ++nt) {
            v8bf bf = *(const v8bf*)(encwf + ((size_t)kc * 8 + nt) * 512 + lane * 8);
            acc[nt] = __builtin_amdgcn_mfma_f32_16x16x32_bf16(af, bf, acc[nt], 0, 0, 0);
        }
    }
    #pragma unroll
    for (int nt = 0; nt < 8; ++nt) {
        const float bias = encb[nt * 16 + m];
        #pragma unroll
        for (int rg = 0; rg < 4; ++rg) {
            float v = acc[nt][rg] + bias;
            v = v > 0.f ? v : 0.f;
            tb[wv][(q * 4 + rg) * 136 + nt * 16 + m] = (__bf16)v;
        }
    }
    const int rt = blockIdx.x * 4 + wv;
    #pragma unroll
    for (int kc = 0; kc < 4; ++kc) {
        v8bf v = *(const v8bf*)&tb[wv][m * 136 + kc * 32 + q * 8];
        *(v8bf*)(enct + ((size_t)(rt * 4 + kc) * 64 + lane) * 16) = v;
    }
}

// ---------------- critic: GT=2, depth-2 triple-buffer (R5 structure), packed amx ----------------
#define LD_E(D, KC, GG) \
  { _Pragma("unroll") \
    for (int mt_ = 0; mt_ < 4; ++mt_) \
      D[mt_] = *(const v8bf*)(encL + (GG) * 65536 + mt_ * 4096 + (KC) * 1024); }

#define LD_4(D, GG) \
  { _Pragma("unroll") \
    for (int mt_ = 0; mt_ < 4; ++mt_) \
      D[mt_] = *(const v8bf*)(a4L + (GG) * 8192 + mt_ * 512); }

#define LD_5(D, GG) \
  { _Pragma("unroll") \
    for (int mt_ = 0; mt_ < 4; ++mt_) \
      D[mt_] = *(const v8bf*)(a5L + (GG) * g5 + mt_ * s5); }

// swapped operand order: A = W1 fragment (from LDS), B = X fragment (per-lane rows).
// setprio(1) keeps the MFMA wave favored while sibling waves run epilogue VALU (phase-diverse).
#define MFMA_KC(AF, KC) \
  { __builtin_amdgcn_s_setprio(1); \
    _Pragma("unroll") \
    for (int nt_ = 0; nt_ < 8; ++nt_) { \
      v8bf bf_ = *(const v8bf*)&w1s[(size_t)(((KC) * 8 + nt_) * 512) + lane * 8]; \
      acc[0][nt_] = __builtin_amdgcn_mfma_f32_16x16x32_bf16(bf_, AF[0], acc[0][nt_], 0, 0, 0); \
      acc[1][nt_] = __builtin_amdgcn_mfma_f32_16x16x32_bf16(bf_, AF[1], acc[1][nt_], 0, 0, 0); \
      acc[2][nt_] = __builtin_amdgcn_mfma_f32_16x16x32_bf16(bf_, AF[2], acc[2][nt_], 0, 0, 0); \
      acc[3][nt_] = __builtin_amdgcn_mfma_f32_16x16x32_bf16(bf_, AF[3], acc[3][nt_], 0, 0, 0); \
    } \
    __builtin_amdgcn_s_setprio(0); }

__global__ __launch_bounds__(256, 2) void critic_kernel(
    const float* __restrict__ eb2, const float* __restrict__ ib2,
    const char* __restrict__ ws, float* __restrict__ out)
{
    __shared__ __bf16 w1s[6 * 8 * 512];   // 48 KB W1 panel (incl. bias row), fragment order
    __shared__ __bf16 w2s[16 * 128];      // 4 KB W2 [c][(dlow^c)][dtile]
    __shared__ float  b2s[16];

    const int t = threadIdx.x;
    const int p  = blockIdx.y;
    const int rb = blockIdx.x;
    const int wv = t >> 6, lane = t & 63, m = lane & 15, q = lane >> 4;

    int ai, hj;
    const float* b2;
    float* outp;
    if (p < 12) {
        ai = p / 3; hj = p % 3;
        b2 = eb2 + (size_t)(hj * NA + ai) * Csz;
        outp = out + (size_t)(ai * NH + hj) * Bsz;
    } else {
        const int qq = p - 12; ai = qq >> 1; const int jj = qq & 1; hj = jj + 1;
        b2 = ib2 + (size_t)(jj * NA + ai) * Csz;
        outp = out + (size_t)NA * NH * Bsz + (size_t)(ai * NHI + jj) * Bsz;
    }

    const __bf16* w1f = (const __bf16*)(ws + OFF_W1F) + (size_t)p * 6 * 8 * 512;
    const __bf16* w2t = (const __bf16*)(ws + OFF_W2T) + (size_t)p * 2048;
    // packed argmax: one u32 per (64-row group, m); group = rb*8 + g*4 + wv
    const char* amxL = ws + OFF_AMX + (size_t)(ai * NH + hj) * 32768
        + ((size_t)rb * 8 + wv) * 64 + m * 4;

    // stage W1 panel (48 KB) + W2 (4 KB) + b2 into LDS
    {
        const v8bf* src = (const v8bf*)w1f;
        #pragma unroll
        for (int i = 0; i < 12; ++i)
            ((v8bf*)w1s)[i * 256 + t] = src[i * 256 + t];
        ((v8bf*)w2s)[t] = ((const v8bf*)w2t)[t];
        if (t < 16) b2s[t] = b2[t];
    }

    // slim per-lane X bases (tiled layouts -> base + immediate offsets)
    const int loo0 = 0 + (0 >= ai), loo1 = 1 + (1 >= ai), loo2 = 2 + (2 >= ai);
    const int pA = loo0 * NH + hj, pB = loo1 * NH + hj, pC = loo2 * NH + hj;
    const int rtb = rb * 32 + wv * 4;
    const char* encL = ws + OFF_ENC + (size_t)rtb * 4096 + lane * 16;
    const size_t rtoff = (size_t)rtb * 512 + (lane & 31) * 16;
    const char* a4L = ws + OFF_ACSBF + (size_t)((q < 2) ? pA : pB) * 1048576 + rtoff;
    const char* a5L; int s5, g5;
    if (q < 2) { a5L = ws + OFF_ACSBF + (size_t)pC * 1048576 + rtoff; s5 = 512; g5 = 8192; }
    else       { a5L = ws + OFF_ZERO + (q - 2) * 16;                  s5 = 0;   g5 = 0;    }

    v4f acc[4][8];
    #pragma unroll
    for (int i = 0; i < 4; ++i)
        #pragma unroll
        for (int j = 0; j < 8; ++j)
            acc[i][j] = (v4f){0.f, 0.f, 0.f, 0.f};

    // triple-buffered X fragments: always 2 KCs in flight
    v8bf af0[4], af1[4], af2[4];
    LD_E(af0, 0, 0)
    LD_E(af1, 1, 0)

    __syncthreads();

    #pragma unroll
    for (int g = 0; g < GT; ++g) {
        // this g's packed argmax word: 1 load, consumed ~6 MFMA clusters later
        const unsigned int cw = *(const unsigned int*)(amxL + g * 256);

        LD_E(af2, 2, g)  MFMA_KC(af0, 0)
        LD_E(af0, 3, g)  MFMA_KC(af1, 1)
        LD_4(af1, g)     MFMA_KC(af2, 2)
        LD_5(af2, g)     MFMA_KC(af0, 3)
        if (g + 1 < GT) { LD_E(af0, 0, g + 1) }
        MFMA_KC(af1, 4)
        if (g + 1 < GT) { LD_E(af1, 1, g + 1) }
        MFMA_KC(af2, 5)

        // epilogue: lane holds z[d = nt*16 + q*4 + rg] of row (mt*16 + m); bias folded in GEMM.
        #pragma unroll
        for (int mt = 0; mt < 4; ++mt) {
            const int c = (int)((cw >> (8 * mt)) & 255u);
            const __bf16* wcb = &w2s[c * 128];
            float s0 = 0.f, s1 = 0.f;
            #pragma unroll
            for (int rg = 0; rg < 4; rg += 2) {
                const v8bf wa = *(const v8bf*)&wcb[((q * 4 + rg) ^ c) * 8];
                const v8bf wb = *(const v8bf*)&wcb[((q * 4 + rg + 1) ^ c) * 8];
                #pragma unroll
                for (int nt = 0; nt < 8; ++nt) {
                    s0 += fmaxf(acc[mt][nt][rg],     0.f) * (float)wa[nt];
                    s1 += fmaxf(acc[mt][nt][rg + 1], 0.f) * (float)wb[nt];
                }
            }
            float tsum = s0 + s1;
            tsum += __shfl_xor(tsum, 16, 64);
            tsum += __shfl_xor(tsum, 32, 64);
            if (q == 0)
                outp[(size_t)rb * 512 + g * 256 + wv * 64 + mt * 16 + m] = tsum + b2s[c];
            if (g + 1 < GT) {
                #pragma unroll
                for (int nt = 0; nt < 8; ++nt) acc[mt][nt] = (v4f){0.f, 0.f, 0.f, 0.f};
            }
        }
    }
}

extern "C" void kernel_launch(void* const* d_in, const int* in_sizes, int n_in,
                              void* d_out, int out_size, void* d_ws, size_t ws_size,
                              hipStream_t stream) {
    const float* sv   = (const float*)d_in[0];
    const float* acs  = (const float*)d_in[1];
    const float* encW = (const float*)d_in[2];
    const float* encb = (const float*)d_in[3];
    const float* eW1  = (const float*)d_in[4];
    const float* eb1  = (const float*)d_in[5];
    const float* eW2  = (const float*)d_in[6];
    const float* eb2  = (const float*)d_in[7];
    const float* iW1  = (const float*)d_in[8];
    const float* ib1  = (const float*)d_in[9];
    const float* iW2  = (const float*)d_in[10];
    const float* ib2  = (const float*)d_in[11];
    float* out = (float*)d_out;
    char* ws = (char*)d_ws;

    hipLaunchKernelGGL(prep_kernel, dim3((N_PREP + 255) / 256), dim3(256), 0, stream,
                       acs, encW, eW1, iW1, eW2, iW2, eb1, ib1, ws);
    hipLaunchKernelGGL(enc_kernel, dim3(Bsz / 64), dim3(256), 0, stream, sv, encb, ws);
    hipLaunchKernelGGL(critic_kernel, dim3(Bsz / 512, NP), dim3(256), 0, stream,
                       eb2, ib2, ws, out);
}

// Round 8
// 150.023 us; speedup vs baseline: 1.0702x; 1.0031x over previous
//
#include <hip/hip_runtime.h>

#define NA 4
#define NH 3
#define NHI 2
#define Bsz 32768
#define Ssz 256
#define Csz 16
#define Dsz 128
#define INsz 176
#define NP 20
#define KP 192
#define GT 2

typedef __bf16 v8bf __attribute__((ext_vector_type(8)));
typedef float v4f __attribute__((ext_vector_type(4)));

// ---- ws layout (bytes) ----
// X column order is REORDERED to [enc(0..127) | acs-LOO(128..175) | bias(176) | 0(177..191)],
// baked into the W1F permutation below.
#define OFF_ENC    0                    // enc_t tiled: [rt=B/16][16 chunks][lane][8bf16] = 8388608
#define OFF_ACSBF  8388608              // acs_t tiled: [plane 12][rt 2048][32][8bf16] = 12582912 (1 MiB/plane)
#define OFF_W1F    20971520             // NP*6*8*512*2       = 983040  (fragment-order, new col order)
#define OFF_ENCWF  21954560             // 8*8*512*2          = 65536   (fragment-order)
#define OFF_W2T    22020096             // NP*2048*2 bf16, layout [p][c][(dlow^c)][dtile]
#define OFF_AMX    22102016             // amx2 packed: [plane 12][group B/64][m 16] u32 = 393216
#define OFF_ZERO   22495232             // 64 B: bf16 {1.0, 0...} then zeros (bias one-hot + zero pad)

// ---- prep ranges ----
#define N_ACSROW (NA*NH*Bsz)            // 393216
#define N_W1F   (NP*192*32)             // 122880
#define N_ENCWF (256*32)                // 8192
#define N_W2T   (NP*Csz*Dsz)            // 40960
#define N_ZERO  16
#define N_PREP  (N_ACSROW+N_W1F+N_ENCWF+N_W2T+N_ZERO)

__global__ __launch_bounds__(256) void prep_kernel(
    const float* __restrict__ acs, const float* __restrict__ encW,
    const float* __restrict__ eW1, const float* __restrict__ iW1,
    const float* __restrict__ eW2, const float* __restrict__ iW2,
    const float* __restrict__ eb1, const float* __restrict__ ib1,
    char* __restrict__ ws)
{
    long tid = (long)blockIdx.x * 256 + threadIdx.x;

    if (tid < N_ACSROW) {          // acs row: fp32->bf16 + argmax; store TILED [plane][rt][qh*16+m][8]
        const float4* src = (const float4*)(acs + (size_t)tid * 16);
        float4 f0 = src[0], f1 = src[1], f2 = src[2], f3 = src[3];
        float v[16] = {f0.x,f0.y,f0.z,f0.w, f1.x,f1.y,f1.z,f1.w,
                       f2.x,f2.y,f2.z,f2.w, f3.x,f3.y,f3.z,f3.w};
        v8bf o0, o1;
        #pragma unroll
        for (int i = 0; i < 8; ++i) { o0[i] = (__bf16)v[i]; o1[i] = (__bf16)v[8 + i]; }
        const int plane = (int)(tid >> 15);          // tid / Bsz
        const int b     = (int)(tid & 32767);
        const int rt    = b >> 4, mm = b & 15;
        char* dstb = ws + OFF_ACSBF + (size_t)plane * 1048576 + (size_t)rt * 512 + mm * 16;
        *(v8bf*)dstb         = o0;                   // cols 0..7  (chunk 0)
        *(v8bf*)(dstb + 256) = o1;                   // cols 8..15 (chunk 1)
        float best = v[0]; int bi = 0;
        #pragma unroll
        for (int c = 1; c < 16; ++c) if (v[c] > best) { best = v[c]; bi = c; }
        // amx2 packed layout: u32 per (64-row group, m); byte mt of word = argmax(grp*64 + mt*16 + m)
        const int grp = b >> 6, mt = (b >> 4) & 3, m = b & 15;
        ((unsigned char*)(ws + OFF_AMX))[(size_t)plane * 32768 + grp * 64 + m * 4 + mt]
            = (unsigned char)bi;
        return;
    }
    tid -= N_ACSROW;
    if (tid < N_W1F) {             // W1 -> bf16 fragment-order [p][kc][nt][lane][8], REORDERED cols:
        const int n4 = (int)(tid & 31) * 4;          // k'<128: enc (src row 48+k'); 128..175: acs (k'-128);
        const int k  = (int)((tid >> 5) % 192);      // 176: b1; else 0
        const int p  = (int)(tid / 6144);
        const float* W1; const float* B1;
        if (p < 12) { int ai = p / 3, hj = p % 3; int wi = hj * NA + ai;
                      W1 = eW1 + (size_t)wi * INsz * Dsz; B1 = eb1 + (size_t)wi * Dsz; }
        else { int qq = p - 12; int ai = qq >> 1, jj = qq & 1; int wi = jj * NA + ai;
               W1 = iW1 + (size_t)wi * INsz * Dsz; B1 = ib1 + (size_t)wi * Dsz; }
        float4 f;
        if (k < 128)        f = *(const float4*)(W1 + (size_t)(48 + k) * Dsz + n4);
        else if (k < INsz)  f = *(const float4*)(W1 + (size_t)(k - 128) * Dsz + n4);
        else if (k == INsz) f = *(const float4*)(B1 + n4);
        else                f = (float4){0.f, 0.f, 0.f, 0.f};
        const int kc = k >> 5, q = (k >> 3) & 3, j = k & 7;
        __bf16* dst = (__bf16*)(ws + OFF_W1F);
        const float fv[4] = {f.x, f.y, f.z, f.w};
        #pragma unroll
        for (int i = 0; i < 4; ++i) {
            const int n = n4 + i, nt = n >> 4, m = n & 15;
            dst[((size_t)(p * 6 + kc) * 8 + nt) * 512 + (q * 16 + m) * 8 + j] = (__bf16)fv[i];
        }
        return;
    }
    tid -= N_W1F;
    if (tid < N_ENCWF) {           // encW -> bf16 fragment-order [kc][nt][lane][8] (enc GEMM B, unchanged)
        const int n4 = (int)(tid & 31) * 4;
        const int k  = (int)(tid >> 5);
        float4 f = *(const float4*)(encW + (size_t)k * Dsz + n4);
        const int kc = k >> 5, q = (k >> 3) & 3, j = k & 7;
        __bf16* dst = (__bf16*)(ws + OFF_ENCWF);
        const float fv[4] = {f.x, f.y, f.z, f.w};
        #pragma unroll
        for (int i = 0; i < 4; ++i) {
            const int n = n4 + i, nt = n >> 4, m = n & 15;
            dst[((size_t)kc * 8 + nt) * 512 + (q * 16 + m) * 8 + j] = (__bf16)fv[i];
        }
        return;
    }
    tid -= N_ENCWF;
    if (tid < N_W2T) {             // W2 -> bf16 [p][c][(dlow^c)][dtile]  (d = dtile*16 + dlow)
        int d = (int)(tid & 127);
        int rest = (int)(tid >> 7);
        int c = rest & 15, p = rest >> 4;
        const float* W2;
        if (p < 12) { int ai = p / 3, hj = p % 3; W2 = eW2 + (size_t)(hj * NA + ai) * Dsz * Csz; }
        else { int qq = p - 12; int ai = qq >> 1, jj = qq & 1; W2 = iW2 + (size_t)(jj * NA + ai) * Dsz * Csz; }
        const int dlow = d & 15, dt = d >> 4;
        ((__bf16*)(ws + OFF_W2T))[(size_t)p * 2048 + c * 128 + ((dlow ^ c) * 8) + dt]
            = (__bf16)W2[(size_t)d * Csz + c];
        return;
    }
    tid -= N_W2T;
    if (tid < N_ZERO) {            // bias one-hot: bytes 0..15 = {1.0bf16,0...}, 16..63 = 0
        ((unsigned int*)(ws + OFF_ZERO))[tid] = (tid == 0) ? 0x00003F80u : 0u;
    }
}

// ---------------- encoder: LDS-staged sv (coalesced HBM), MFMA, per-wave transpose ----------------
// Output layout enc_t: byte = rt*4096 + s*256 + m*16 + j*2  holds enc[rt*16 + m][s*8 + j]
__global__ __launch_bounds__(256) void enc_kernel(const float* __restrict__ sv,
                                                  const float* __restrict__ encb,
                                                  char* __restrict__ ws)
{
    __shared__ __bf16 svs[64][264];      // 33.8 KB: 64 rows x 256 cols (+8 pad), bf16
    __shared__ __bf16 tb[4][16 * 136];   // 17 KB: per-wave output transpose tile

    const int t = threadIdx.x;
    const int wv = t >> 6, lane = t & 63, m = lane & 15, q = lane >> 4;
    const __bf16* encwf = (const __bf16*)(ws + OFF_ENCWF);
    char* enct = ws + OFF_ENC;

    {
        const float* src = sv + ((size_t)blockIdx.x * 64 + wv * 16) * Ssz;
        #pragma unroll
        for (int i = 0; i < 16; ++i) {
            float4 f = *(const float4*)(src + i * Ssz + lane * 4);
            __bf16* d = &svs[wv * 16 + i][lane * 4];
            d[0] = (__bf16)f.x; d[1] = (__bf16)f.y; d[2] = (__bf16)f.z; d[3] = (__bf16)f.w;
        }
    }

    v4f acc[8];
    #pragma unroll
    for (int nt = 0; nt < 8; ++nt) acc[nt] = (v4f){0.f, 0.f, 0.f, 0.f};

    #pragma unroll
    for (int kc = 0; kc < 8; ++kc) {
        v8bf af = *(const v8bf*)&svs[wv * 16 + m][kc * 32 + q * 8];
        #pragma unroll
        for (int nt = 0; nt < 8; ++nt) {
            v8bf bf = *(const v8bf*)(encwf + ((size_t)kc * 8 + nt) * 512 + lane * 8);
            acc[nt] = __builtin_amdgcn_mfma_f32_16x16x32_bf16(af, bf, acc[nt], 0, 0, 0);
        }
    }
    #pragma unroll
    for (int nt = 0; nt < 8; ++nt) {
        const float bias = encb[nt * 16 + m];
        #pragma unroll
        for (int rg = 0; rg < 4; ++rg) {
            float v = acc[nt][rg] + bias;
            v = v > 0.f ? v : 0.f;
            tb[wv][(q * 4 + rg) * 136 + nt * 16 + m] = (__bf16)v;
        }
    }
    const int rt = blockIdx.x * 4 + wv;
    #pragma unroll
    for (int kc = 0; kc < 4; ++kc) {
        v8bf v = *(const v8bf*)&tb[wv][m * 136 + kc * 32 + q * 8];
        *(v8bf*)(enct + ((size_t)(rt * 4 + kc) * 64 + lane) * 16) = v;
    }
}

// ---------------- critic: GT=2, triple-buffer, packed amx, BLOCK-PARITY K-ROTATION ----------------
#define LD_E(D, KC, GG) \
  { _Pragma("unroll") \
    for (int mt_ = 0; mt_ < 4; ++mt_) \
      D[mt_] = *(const v8bf*)(encL + (GG) * 65536 + mt_ * 4096 + (KC) * 1024); }

#define LD_4(D, GG) \
  { _Pragma("unroll") \
    for (int mt_ = 0; mt_ < 4; ++mt_) \
      D[mt_] = *(const v8bf*)(a4L + (GG) * 8192 + mt_ * 512); }

#define LD_5(D, GG) \
  { _Pragma("unroll") \
    for (int mt_ = 0; mt_ < 4; ++mt_) \
      D[mt_] = *(const v8bf*)(a5L + (GG) * g5 + mt_ * s5); }

// swapped operand order: A = W1 fragment (from LDS), B = X fragment (per-lane rows).
// setprio(1) favors the MFMA-phase wave; with K-rotation the SIMD-mate wave is in a
// DIFFERENT phase (ds_read/epilogue), so arbitration has something to do.
#define MFMA_KC(AF, KC) \
  { __builtin_amdgcn_s_setprio(1); \
    _Pragma("unroll") \
    for (int nt_ = 0; nt_ < 8; ++nt_) { \
      v8bf bf_ = *(const v8bf*)&w1s[(size_t)(((KC) * 8 + nt_) * 512) + lane * 8]; \
      acc[0][nt_] = __builtin_amdgcn_mfma_f32_16x16x32_bf16(bf_, AF[0], acc[0][nt_], 0, 0, 0); \
      acc[1][nt_] = __builtin_amdgcn_mfma_f32_16x16x32_bf16(bf_, AF[1], acc[1][nt_], 0, 0, 0); \
      acc[2][nt_] = __builtin_amdgcn_mfma_f32_16x16x32_bf16(bf_, AF[2], acc[2][nt_], 0, 0, 0); \
      acc[3][nt_] = __builtin_amdgcn_mfma_f32_16x16x32_bf16(bf_, AF[3], acc[3][nt_], 0, 0, 0); \
    } \
    __builtin_amdgcn_s_setprio(0); }

#define EPILOG(GG) \
  { _Pragma("unroll") \
    for (int mt = 0; mt < 4; ++mt) { \
        const int c = (int)((cw >> (8 * mt)) & 255u); \
        const __bf16* wcb = &w2s[c * 128]; \
        float s0 = 0.f, s1 = 0.f; \
        _Pragma("unroll") \
        for (int rg = 0; rg < 4; rg += 2) { \
            const v8bf wa = *(const v8bf*)&wcb[((q * 4 + rg) ^ c) * 8]; \
            const v8bf wb = *(const v8bf*)&wcb[((q * 4 + rg + 1) ^ c) * 8]; \
            _Pragma("unroll") \
            for (int nt = 0; nt < 8; ++nt) { \
                s0 += fmaxf(acc[mt][nt][rg],     0.f) * (float)wa[nt]; \
                s1 += fmaxf(acc[mt][nt][rg + 1], 0.f) * (float)wb[nt]; \
            } \
        } \
        float tsum = s0 + s1; \
        tsum += __shfl_xor(tsum, 16, 64); \
        tsum += __shfl_xor(tsum, 32, 64); \
        if (q == 0) \
            outp[(size_t)rb * 512 + (GG) * 256 + wv * 64 + mt * 16 + m] = tsum + b2s[c]; \
        if ((GG) + 1 < GT) { \
            _Pragma("unroll") \
            for (int nt = 0; nt < 8; ++nt) acc[mt][nt] = (v4f){0.f, 0.f, 0.f, 0.f}; \
        } \
    } }

__global__ __launch_bounds__(256, 2) void critic_kernel(
    const float* __restrict__ eb2, const float* __restrict__ ib2,
    const char* __restrict__ ws, float* __restrict__ out)
{
    __shared__ __bf16 w1s[6 * 8 * 512];   // 48 KB W1 panel (incl. bias row), fragment order
    __shared__ __bf16 w2s[16 * 128];      // 4 KB W2 [c][(dlow^c)][dtile]
    __shared__ float  b2s[16];

    const int t = threadIdx.x;
    const int p  = blockIdx.y;
    const int rb = blockIdx.x;
    const int wv = t >> 6, lane = t & 63, m = lane & 15, q = lane >> 4;

    int ai, hj;
    const float* b2;
    float* outp;
    if (p < 12) {
        ai = p / 3; hj = p % 3;
        b2 = eb2 + (size_t)(hj * NA + ai) * Csz;
        outp = out + (size_t)(ai * NH + hj) * Bsz;
    } else {
        const int qq = p - 12; ai = qq >> 1; const int jj = qq & 1; hj = jj + 1;
        b2 = ib2 + (size_t)(jj * NA + ai) * Csz;
        outp = out + (size_t)NA * NH * Bsz + (size_t)(ai * NHI + jj) * Bsz;
    }

    const __bf16* w1f = (const __bf16*)(ws + OFF_W1F) + (size_t)p * 6 * 8 * 512;
    const __bf16* w2t = (const __bf16*)(ws + OFF_W2T) + (size_t)p * 2048;
    // packed argmax: one u32 per (64-row group, m); group = rb*8 + g*4 + wv
    const char* amxL = ws + OFF_AMX + (size_t)(ai * NH + hj) * 32768
        + ((size_t)rb * 8 + wv) * 64 + m * 4;

    // stage W1 panel (48 KB) + W2 (4 KB) + b2 into LDS
    {
        const v8bf* src = (const v8bf*)w1f;
        #pragma unroll
        for (int i = 0; i < 12; ++i)
            ((v8bf*)w1s)[i * 256 + t] = src[i * 256 + t];
        ((v8bf*)w2s)[t] = ((const v8bf*)w2t)[t];
        if (t < 16) b2s[t] = b2[t];
    }

    // slim per-lane X bases (tiled layouts -> base + immediate offsets)
    const int loo0 = 0 + (0 >= ai), loo1 = 1 + (1 >= ai), loo2 = 2 + (2 >= ai);
    const int pA = loo0 * NH + hj, pB = loo1 * NH + hj, pC = loo2 * NH + hj;
    const int rtb = rb * 32 + wv * 4;
    const char* encL = ws + OFF_ENC + (size_t)rtb * 4096 + lane * 16;
    const size_t rtoff = (size_t)rtb * 512 + (lane & 31) * 16;
    const char* a4L = ws + OFF_ACSBF + (size_t)((q < 2) ? pA : pB) * 1048576 + rtoff;
    const char* a5L; int s5, g5;
    if (q < 2) { a5L = ws + OFF_ACSBF + (size_t)pC * 1048576 + rtoff; s5 = 512; g5 = 8192; }
    else       { a5L = ws + OFF_ZERO + (q - 2) * 16;                  s5 = 0;   g5 = 0;    }

    v4f acc[4][8];
    #pragma unroll
    for (int i = 0; i < 4; ++i)
        #pragma unroll
        for (int j = 0; j < 8; ++j)
            acc[i][j] = (v4f){0.f, 0.f, 0.f, 0.f};

    // triple-buffered X fragments: always 2 KCs in flight.
    // Block-parity K-rotation: odd blocks run KC order 3,4,5,0,1,2 so SIMD-mate waves
    // (consecutive blocks on a CU) sit half a K-loop out of phase -> MFMA/ds_read/epilogue
    // phases interleave across waves instead of lockstep-contending.
    v8bf af0[4], af1[4], af2[4];

    if (((rb + p) & 1) == 0) {
        LD_E(af0, 0, 0)
        LD_E(af1, 1, 0)
        __syncthreads();
        #pragma unroll
        for (int g = 0; g < GT; ++g) {
            const unsigned int cw = *(const unsigned int*)(amxL + g * 256);
            LD_E(af2, 2, g)  MFMA_KC(af0, 0)
            LD_E(af0, 3, g)  MFMA_KC(af1, 1)
            LD_4(af1, g)     MFMA_KC(af2, 2)
            LD_5(af2, g)     MFMA_KC(af0, 3)
            if (g + 1 < GT) { LD_E(af0, 0, g + 1) }
            MFMA_KC(af1, 4)
            if (g + 1 < GT) { LD_E(af1, 1, g + 1) }
            MFMA_KC(af2, 5)
            EPILOG(g)
        }
    } else {
        LD_E(af0, 3, 0)
        LD_4(af1, 0)
        __syncthreads();
        #pragma unroll
        for (int g = 0; g < GT; ++g) {
            const unsigned int cw = *(const unsigned int*)(amxL + g * 256);
            LD_5(af2, g)     MFMA_KC(af0, 3)
            LD_E(af0, 0, g)  MFMA_KC(af1, 4)
            LD_E(af1, 1, g)  MFMA_KC(af2, 5)
            LD_E(af2, 2, g)  MFMA_KC(af0, 0)
            if (g + 1 < GT) { LD_E(af0, 3, g + 1) }
            MFMA_KC(af1, 1)
            if (g + 1 < GT) { LD_4(af1, g + 1) }
            MFMA_KC(af2, 2)
            EPILOG(g)
        }
    }
}

extern "C" void kernel_launch(void* const* d_in, const int* in_sizes, int n_in,
                              void* d_out, int out_size, void* d_ws, size_t ws_size,
                              hipStream_t stream) {
    const float* sv   = (const float*)d_in[0];
    const float* acs  = (const float*)d_in[1];
    const float* encW = (const float*)d_in[2];
    const float* encb = (const float*)d_in[3];
    const float* eW1  = (const float*)d_in[4];
    const float* eb1  = (const float*)d_in[5];
    const float* eW2  = (const float*)d_in[6];
    const float* eb2  = (const float*)d_in[7];
    const float* iW1  = (const float*)d_in[8];
    const float* ib1  = (const float*)d_in[9];
    const float* iW2  = (const float*)d_in[10];
    const float* ib2  = (const float*)d_in[11];
    float* out = (float*)d_out;
    char* ws = (char*)d_ws;

    hipLaunchKernelGGL(prep_kernel, dim3((N_PREP + 255) / 256), dim3(256), 0, stream,
                       acs, encW, eW1, iW1, eW2, iW2, eb1, ib1, ws);
    hipLaunchKernelGGL(enc_kernel, dim3(Bsz / 64), dim3(256), 0, stream, sv, encb, ws);
    hipLaunchKernelGGL(critic_kernel, dim3(Bsz / 512, NP), dim3(256), 0, stream,
                       eb2, ib2, ws, out);
}